// Round 5
// baseline (97.309 us; speedup 1.0000x reference)
//
#include <hip/hip_runtime.h>
#include <hip/hip_bf16.h>
#include <float.h>

#define DIMS 64
#define KC 1024
#define M_TOTAL 65536
#define TAU 4e-3f   // split-bf16 dist err ~2e-5 std -> ~200 sigma margin

typedef __attribute__((ext_vector_type(8))) short bf16x8;   // 8 bf16 = 4 VGPRs
typedef __attribute__((ext_vector_type(4))) float f32x4;

// ---------------- ws layout (float elements) ----------------
#define SE_OFF   0            // 1024 f32 codebook sq norms
#define CTL_OFF  1024         // [0]=refine cnt, [1]=done ticket, [2..3]=i64 loss acc
#define PBH_OFF  2048         // 65536 bf16 hi frags (32768 f32)
#define PBL_OFF  34816        // 65536 bf16 lo frags
#define WL_OFF   67584        // 65536 int worklist
#define IDX_OFF  133120       // 65536 int argmin per row

#define LOSS_SCALE 1048576.0  // 2^20 fixed point

__device__ inline short f2bf(float x) {
  union { __hip_bfloat16 h; short s; } u;
  u.h = __float2bfloat16(x);
  return u.s;
}
__device__ inline float bf2f(short x) {
  union { short s; __hip_bfloat16 h; } u;
  u.s = x;
  return __bfloat162float(u.h);
}

// async global->LDS, 16B per lane; lptr must be wave-uniform (dest = lptr + lane*16)
__device__ inline void gload_lds16(const void* g, void* l) {
  __builtin_amdgcn_global_load_lds(
      (const __attribute__((address_space(1))) void*)g,
      (__attribute__((address_space(3))) void*)l, 16, 0, 0);
}

// fused: pack codebook into bf16 MFMA B-fragment layout (hi + lo residue) + sq norms + zero ctl
// frag[((tile*2 + ks)*64 + lane)*8 + j] = E[16*tile + (lane&15)][32*ks + (lane>>4)*8 + j]
__global__ __launch_bounds__(256) void k_prep(const float* __restrict__ cb,
                                              float* __restrict__ se,
                                              unsigned int* __restrict__ ctl,
                                              unsigned short* __restrict__ pbh,
                                              unsigned short* __restrict__ pbl) {
  const int tid = blockIdx.x * 256 + threadIdx.x;  // 8192 total
  if (tid < 4) ctl[tid] = 0;  // cnt, ticket, loss acc lo/hi
  const int l = tid & 63;
  const int s = (tid >> 6) & 1;
  const int tt = tid >> 7;
  const int code = tt * 16 + (l & 15);
  const int k = s * 32 + (l >> 4) * 8;
  const float* p = cb + (size_t)code * DIMS + k;
  float v[8];
  ((float4*)v)[0] = ((const float4*)p)[0];
  ((float4*)v)[1] = ((const float4*)p)[1];
  bf16x8 h, lo;
#pragma unroll
  for (int j = 0; j < 8; ++j) {
    short hj = f2bf(v[j]);
    h[j] = hj;
    lo[j] = f2bf(v[j] - bf2f(hj));
  }
  *(bf16x8*)(pbh + (size_t)tid * 8) = h;
  *(bf16x8*)(pbl + (size_t)tid * 8) = lo;

  if (tid < KC) {
    const float4* q = (const float4*)(cb + (size_t)tid * DIMS);
    float a0 = 0.f, a1 = 0.f, a2 = 0.f, a3 = 0.f;
#pragma unroll
    for (int i = 0; i < DIMS / 4; ++i) {
      float4 u = q[i];
      a0 = fmaf(u.x, u.x, a0);
      a1 = fmaf(u.y, u.y, a1);
      a2 = fmaf(u.z, u.z, a2);
      a3 = fmaf(u.w, u.w, a3);
    }
    se[tid] = (a0 + a1) + (a2 + a3);
  }
}

// MFMA phase-1 (split bf16): block = 4 waves x 16 rows, all 1024 codes.
// B staged in LDS (32-code chunks, double-buffered), shared by all 4 waves.
// C/D layout (m89-verified): col = lane&15, row = (lane>>4)*4 + reg.
__global__ __launch_bounds__(256, 4) void k_dist(const float* __restrict__ z,
                                                 const unsigned short* __restrict__ pbh,
                                                 const unsigned short* __restrict__ pbl,
                                                 const float* __restrict__ se,
                                                 int* __restrict__ idxo,
                                                 int* __restrict__ wl,
                                                 unsigned int* __restrict__ ctl) {
  __shared__ bf16x8 sB[2][2][256];  // [buf][hi/lo][frag] = 16 KB
  const int l = threadIdx.x & 63;
  const int w = threadIdx.x >> 6;
  const int r0 = blockIdx.x * 64 + w * 16;
  const int col = l & 15;
  const int g = l >> 4;

  // A fragments (hi + lo residue), 2 ksteps of 32
  bf16x8 ah[2], al[2];
  {
    const float* zp = z + (size_t)(r0 + col) * DIMS + g * 8;
#pragma unroll
    for (int ks = 0; ks < 2; ++ks) {
      float v[8];
      ((float4*)v)[0] = ((const float4*)(zp + ks * 32))[0];
      ((float4*)v)[1] = ((const float4*)(zp + ks * 32))[1];
#pragma unroll
      for (int j = 0; j < 8; ++j) {
        short hj = f2bf(v[j]);
        ah[ks][j] = hj;
        al[ks][j] = f2bf(v[j] - bf2f(hj));
      }
    }
  }

  float m1[4] = {FLT_MAX, FLT_MAX, FLT_MAX, FLT_MAX};
  float m2[4] = {FLT_MAX, FLT_MAX, FLT_MAX, FLT_MAX};
  int bt[4] = {0, 0, 0, 0};

  // stage chunk 0 (8 KB: 256 hi frags + 256 lo frags; 2 gload_lds per thread)
  {
    const int f = w * 64 + l;
    gload_lds16(pbh + (size_t)f * 8, &sB[0][0][w * 64]);
    gload_lds16(pbl + (size_t)f * 8, &sB[0][1][w * 64]);
  }
  __syncthreads();

  int cur = 0;
  for (int c = 0; c < 32; ++c) {           // 32 chunks x 32 codes
    if (c + 1 < 32) {
      const size_t f = (size_t)(c + 1) * 256 + w * 64 + l;
      gload_lds16(pbh + f * 8, &sB[cur ^ 1][0][w * 64]);
      gload_lds16(pbl + f * 8, &sB[cur ^ 1][1][w * 64]);
    }
#pragma unroll
    for (int tt = 0; tt < 2; ++tt) {       // 2 tiles of 16 codes
      const int t = c * 2 + tt;
      bf16x8 bh0 = sB[cur][0][tt * 128 + l];
      bf16x8 bh1 = sB[cur][0][tt * 128 + 64 + l];
      bf16x8 bl0 = sB[cur][1][tt * 128 + l];
      bf16x8 bl1 = sB[cur][1][tt * 128 + 64 + l];
      const float sec = se[t * 16 + col];
      f32x4 acc = {0.f, 0.f, 0.f, 0.f};
      acc = __builtin_amdgcn_mfma_f32_16x16x32_bf16(ah[0], bh0, acc, 0, 0, 0);
      acc = __builtin_amdgcn_mfma_f32_16x16x32_bf16(ah[1], bh1, acc, 0, 0, 0);
      acc = __builtin_amdgcn_mfma_f32_16x16x32_bf16(ah[0], bl0, acc, 0, 0, 0);
      acc = __builtin_amdgcn_mfma_f32_16x16x32_bf16(ah[1], bl1, acc, 0, 0, 0);
      acc = __builtin_amdgcn_mfma_f32_16x16x32_bf16(al[0], bh0, acc, 0, 0, 0);
      acc = __builtin_amdgcn_mfma_f32_16x16x32_bf16(al[1], bh1, acc, 0, 0, 0);
#pragma unroll
      for (int j = 0; j < 4; ++j) {
        float d = fmaf(-2.f, acc[j], sec);
        float nm2 = __builtin_amdgcn_fmed3f(d, m1[j], m2[j]);  // new 2nd-min
        bool lt = d < m1[j];
        m1[j] = lt ? d : m1[j];
        bt[j] = lt ? t : bt[j];
        m2[j] = nm2;
      }
    }
    __syncthreads();
    cur ^= 1;
  }

  // cross-lane reduce over the 16 cols of each row group; lowest-index tie-break
#pragma unroll
  for (int j = 0; j < 4; ++j) {
    float m1j = m1[j], m2j = m2[j];
    int ij = bt[j] * 16 + col;
    for (int msk = 1; msk <= 8; msk <<= 1) {
      float o1 = __shfl_xor(m1j, msk);
      float o2 = __shfl_xor(m2j, msk);
      int oi = __shfl_xor(ij, msk);
      bool take = (o1 < m1j) || (o1 == m1j && oi < ij);
      float hi = take ? m1j : o1;  // losing min1 becomes min2 candidate
      m2j = fminf(fminf(m2j, o2), hi);
      m1j = take ? o1 : m1j;
      ij = take ? oi : ij;
    }
    if (col == 0) {
      const int row = r0 + g * 4 + j;
      idxo[row] = ij;
      if (m2j - m1j < TAU) {
        int p = atomicAdd((int*)ctl, 1);
        wl[p] = row;
      }
    }
  }
}

// exact fp64 diff-form re-resolution for flagged rows (worklist, ~0.3% of rows)
__global__ __launch_bounds__(256) void k_refine(const float* __restrict__ z,
                                                const float* __restrict__ cb,
                                                const int* __restrict__ wl,
                                                const unsigned int* __restrict__ ctl,
                                                int* __restrict__ idxo) {
  __shared__ float zz[64];
  __shared__ double sd[256];
  __shared__ int si[256];
  const int t = threadIdx.x;
  const int n = (int)ctl[0];
  for (int wi = blockIdx.x; wi < n; wi += 2048) {
    const int row = wl[wi];
    if (t < 16) ((float4*)zz)[t] = ((const float4*)(z + (size_t)row * DIMS))[t];
    __syncthreads();
    const int c0 = t * 4;
    double accd[4] = {0.0, 0.0, 0.0, 0.0};
    for (int ch = 0; ch < 4; ++ch) {
      float zr[16];
#pragma unroll
      for (int q = 0; q < 4; ++q) ((float4*)zr)[q] = ((float4*)zz)[ch * 4 + q];
#pragma unroll
      for (int cc = 0; cc < 4; ++cc) {
        const float* e = cb + (size_t)(c0 + cc) * DIMS + ch * 16;
#pragma unroll
        for (int q = 0; q < 16; ++q) {
          double df = (double)zr[q] - (double)e[q];
          accd[cc] = fma(df, df, accd[cc]);
        }
      }
    }
    double best = 1e300;
    int bi = 0;
#pragma unroll
    for (int cc = 0; cc < 4; ++cc)
      if (accd[cc] < best) { best = accd[cc]; bi = c0 + cc; }
    sd[t] = best;
    si[t] = bi;
    __syncthreads();
    for (int off = 128; off > 0; off >>= 1) {
      if (t < off) {
        double ob = sd[t + off];
        int oi = si[t + off];
        if (ob < sd[t] || (ob == sd[t] && oi < si[t])) { sd[t] = ob; si[t] = oi; }
      }
      __syncthreads();
    }
    if (t == 0) idxo[row] = si[0];
    __syncthreads();
  }
}

// gather + straight-through output (z + (e - z), ref rounding) + fixed-point loss + last-block write
__global__ __launch_bounds__(256) void k_out(const float* __restrict__ z,
                                             const float* __restrict__ cb,
                                             const int* __restrict__ idxi,
                                             float* __restrict__ out,
                                             unsigned int* __restrict__ ctl) {
  const int tid = blockIdx.x * 256 + threadIdx.x;  // 262144: quarter-row each
  const int row = tid >> 2;
  const int q = tid & 3;
  const int code = idxi[row];
  const float4* zp = (const float4*)(z + (size_t)row * DIMS + q * 16);
  const float4* ep = (const float4*)(cb + (size_t)code * DIMS + q * 16);
  float4* op = (float4*)(out + (size_t)row * DIMS + q * 16);
  float sse = 0.f;
#pragma unroll
  for (int i = 0; i < 4; ++i) {
    float4 v = zp[i], e = ep[i];
    float dx = e.x - v.x, dy = e.y - v.y, dz = e.z - v.z, dw = e.w - v.w;
    sse = fmaf(dx, dx, sse);
    sse = fmaf(dy, dy, sse);
    sse = fmaf(dz, dz, sse);
    sse = fmaf(dw, dw, sse);
    float4 o;
    o.x = v.x + dx;
    o.y = v.y + dy;
    o.z = v.z + dz;
    o.w = v.w + dw;
    op[i] = o;
  }
  __shared__ float sh[256];
  sh[threadIdx.x] = sse;
  __syncthreads();
  for (int off = 128; off > 0; off >>= 1) {
    if (threadIdx.x < off) sh[threadIdx.x] += sh[threadIdx.x + off];
    __syncthreads();
  }
  if (threadIdx.x == 0) {
    unsigned long long* acc = (unsigned long long*)(ctl + 2);
    // integer fixed-point: order-independent => deterministic across replays
    atomicAdd(acc, (unsigned long long)(long long)llrintf(sh[0] * (float)LOSS_SCALE));
    __threadfence();
    unsigned int done = atomicAdd(ctl + 1, 1u);
    if (done == gridDim.x - 1) {
      unsigned long long v = atomicAdd(acc, 0ULL);
      double sse_tot = (double)(long long)v * (1.0 / LOSS_SCALE);
      // (0.1*mse + mse) * 10 = 11 * SSE / (M*D)
      out[(size_t)M_TOTAL * DIMS] = (float)(sse_tot * 11.0 / ((double)M_TOTAL * DIMS));
    }
  }
}

extern "C" void kernel_launch(void* const* d_in, const int* in_sizes, int n_in,
                              void* d_out, int out_size, void* d_ws, size_t ws_size,
                              hipStream_t stream) {
  const float* z = (const float*)d_in[0];
  const float* cb = (const float*)d_in[1];
  float* out = (float*)d_out;
  float* ws = (float*)d_ws;

  float* se = ws + SE_OFF;
  unsigned int* ctl = (unsigned int*)(ws + CTL_OFF);
  unsigned short* pbh = (unsigned short*)(ws + PBH_OFF);
  unsigned short* pbl = (unsigned short*)(ws + PBL_OFF);
  int* wl = (int*)(ws + WL_OFF);
  int* idx = (int*)(ws + IDX_OFF);

  k_prep<<<32, 256, 0, stream>>>(cb, se, ctl, pbh, pbl);
  k_dist<<<M_TOTAL / 64, 256, 0, stream>>>(z, pbh, pbl, se, idx, wl, ctl);
  k_refine<<<2048, 256, 0, stream>>>(z, cb, wl, ctl, idx);
  k_out<<<M_TOTAL / 64, 256, 0, stream>>>(z, cb, idx, out, ctl);
}

// Round 6
// 60.027 us; speedup vs baseline: 1.6211x; 1.6211x over previous
//
#include <hip/hip_runtime.h>
#include <hip/hip_bf16.h>
#include <float.h>

#define DIMS 64
#define KC 1024
#define M_TOTAL 65536
#define TAU 4e-3f   // split-bf16 dist err ~2e-5 std -> ~200 sigma margin

typedef __attribute__((ext_vector_type(8))) short bf16x8;   // 8 bf16 = 4 VGPRs
typedef __attribute__((ext_vector_type(4))) float f32x4;

// ---------------- ws layout (float elements) ----------------
#define SE_OFF   0            // 1024 f32 codebook sq norms
#define CTL_OFF  1024         // [0]=refine cnt
#define PART_OFF 2048         // 1024 f32 loss partials
#define PBH_OFF  4096         // 65536 bf16 hi frags (32768 f32)
#define PBL_OFF  36864        // 65536 bf16 lo frags
#define WL_OFF   69632        // 65536 int worklist
#define IDX_OFF  135168       // 65536 int argmin per row

__device__ inline short f2bf(float x) {
  union { __hip_bfloat16 h; short s; } u;
  u.h = __float2bfloat16(x);
  return u.s;
}
__device__ inline float bf2f(short x) {
  union { short s; __hip_bfloat16 h; } u;
  u.s = x;
  return __bfloat162float(u.h);
}

// async global->LDS, 16B per lane; lds dest must be wave-uniform (HW writes dest + lane*16)
__device__ inline void gload_lds16(const void* g, void* l) {
  __builtin_amdgcn_global_load_lds(
      (const __attribute__((address_space(1))) void*)g,
      (__attribute__((address_space(3))) void*)l, 16, 0, 0);
}

// fused: pack codebook into bf16 MFMA B-fragment layout (hi + lo residue) + sq norms + zero ctl
// frag[((tile*2 + ks)*64 + lane)*8 + j] = E[16*tile + (lane&15)][32*ks + (lane>>4)*8 + j]
__global__ __launch_bounds__(256) void k_prep(const float* __restrict__ cb,
                                              float* __restrict__ se,
                                              unsigned int* __restrict__ ctl,
                                              unsigned short* __restrict__ pbh,
                                              unsigned short* __restrict__ pbl) {
  const int tid = blockIdx.x * 256 + threadIdx.x;  // 8192 total
  if (tid < 4) ctl[tid] = 0;
  const int l = tid & 63;
  const int s = (tid >> 6) & 1;
  const int tt = tid >> 7;
  const int code = tt * 16 + (l & 15);
  const int k = s * 32 + (l >> 4) * 8;
  const float* p = cb + (size_t)code * DIMS + k;
  float v[8];
  ((float4*)v)[0] = ((const float4*)p)[0];
  ((float4*)v)[1] = ((const float4*)p)[1];
  bf16x8 h, lo;
#pragma unroll
  for (int j = 0; j < 8; ++j) {
    short hj = f2bf(v[j]);
    h[j] = hj;
    lo[j] = f2bf(v[j] - bf2f(hj));
  }
  *(bf16x8*)(pbh + (size_t)tid * 8) = h;
  *(bf16x8*)(pbl + (size_t)tid * 8) = lo;

  if (tid < KC) {
    const float4* q = (const float4*)(cb + (size_t)tid * DIMS);
    float a0 = 0.f, a1 = 0.f, a2 = 0.f, a3 = 0.f;
#pragma unroll
    for (int i = 0; i < DIMS / 4; ++i) {
      float4 u = q[i];
      a0 = fmaf(u.x, u.x, a0);
      a1 = fmaf(u.y, u.y, a1);
      a2 = fmaf(u.z, u.z, a2);
      a3 = fmaf(u.w, u.w, a3);
    }
    se[tid] = (a0 + a1) + (a2 + a3);
  }
}

// MFMA phase-1 (split bf16): block = 4 waves x 32 rows (2 row-sets share each B reg),
// all 1024 codes; B staged in LDS (32-code chunks, double-buffered), shared by 4 waves.
// C/D layout (m89-verified): col = lane&15, row = (lane>>4)*4 + reg.
__global__ __launch_bounds__(256, 2) void k_dist(const float* __restrict__ z,
                                                 const unsigned short* __restrict__ pbh,
                                                 const unsigned short* __restrict__ pbl,
                                                 const float* __restrict__ se,
                                                 int* __restrict__ idxo,
                                                 int* __restrict__ wl,
                                                 unsigned int* __restrict__ ctl) {
  __shared__ bf16x8 sB[2][2][256];  // [buf][hi/lo][frag] = 16 KB
  const int l = threadIdx.x & 63;
  const int w = threadIdx.x >> 6;
  const int r0 = blockIdx.x * 128 + w * 32;  // wave owns rows r0..r0+31
  const int col = l & 15;
  const int g = l >> 4;

  // A fragments (hi + lo residue), 2 row-sets x 2 ksteps of 32
  bf16x8 ah[2][2], al[2][2];
#pragma unroll
  for (int rs = 0; rs < 2; ++rs) {
    const float* zp = z + (size_t)(r0 + rs * 16 + col) * DIMS + g * 8;
#pragma unroll
    for (int ks = 0; ks < 2; ++ks) {
      float v[8];
      ((float4*)v)[0] = ((const float4*)(zp + ks * 32))[0];
      ((float4*)v)[1] = ((const float4*)(zp + ks * 32))[1];
#pragma unroll
      for (int j = 0; j < 8; ++j) {
        short hj = f2bf(v[j]);
        ah[rs][ks][j] = hj;
        al[rs][ks][j] = f2bf(v[j] - bf2f(hj));
      }
    }
  }

  float m1[2][4], m2[2][4];
  int bt[2][4];
#pragma unroll
  for (int rs = 0; rs < 2; ++rs)
#pragma unroll
    for (int j = 0; j < 4; ++j) {
      m1[rs][j] = FLT_MAX;
      m2[rs][j] = FLT_MAX;
      bt[rs][j] = 0;
    }

  // stage chunk 0 (8 KB: 256 hi + 256 lo frags; 2 gload_lds per thread)
  {
    const int f = w * 64 + l;
    gload_lds16(pbh + (size_t)f * 8, &sB[0][0][w * 64]);
    gload_lds16(pbl + (size_t)f * 8, &sB[0][1][w * 64]);
  }
  __syncthreads();

  int cur = 0;
  for (int c = 0; c < 32; ++c) {           // 32 chunks x 32 codes
    if (c + 1 < 32) {
      const size_t f = (size_t)(c + 1) * 256 + w * 64 + l;
      gload_lds16(pbh + f * 8, &sB[cur ^ 1][0][w * 64]);
      gload_lds16(pbl + f * 8, &sB[cur ^ 1][1][w * 64]);
    }
#pragma unroll
    for (int tt = 0; tt < 2; ++tt) {       // 2 tiles of 16 codes
      const int t = c * 2 + tt;
      bf16x8 bh0 = sB[cur][0][tt * 128 + l];
      bf16x8 bh1 = sB[cur][0][tt * 128 + 64 + l];
      bf16x8 bl0 = sB[cur][1][tt * 128 + l];
      bf16x8 bl1 = sB[cur][1][tt * 128 + 64 + l];
      const float sec = se[t * 16 + col];
      f32x4 acc0 = {0.f, 0.f, 0.f, 0.f};
      f32x4 acc1 = {0.f, 0.f, 0.f, 0.f};
      acc0 = __builtin_amdgcn_mfma_f32_16x16x32_bf16(ah[0][0], bh0, acc0, 0, 0, 0);
      acc1 = __builtin_amdgcn_mfma_f32_16x16x32_bf16(ah[1][0], bh0, acc1, 0, 0, 0);
      acc0 = __builtin_amdgcn_mfma_f32_16x16x32_bf16(ah[0][1], bh1, acc0, 0, 0, 0);
      acc1 = __builtin_amdgcn_mfma_f32_16x16x32_bf16(ah[1][1], bh1, acc1, 0, 0, 0);
      acc0 = __builtin_amdgcn_mfma_f32_16x16x32_bf16(ah[0][0], bl0, acc0, 0, 0, 0);
      acc1 = __builtin_amdgcn_mfma_f32_16x16x32_bf16(ah[1][0], bl0, acc1, 0, 0, 0);
      acc0 = __builtin_amdgcn_mfma_f32_16x16x32_bf16(ah[0][1], bl1, acc0, 0, 0, 0);
      acc1 = __builtin_amdgcn_mfma_f32_16x16x32_bf16(ah[1][1], bl1, acc1, 0, 0, 0);
      acc0 = __builtin_amdgcn_mfma_f32_16x16x32_bf16(al[0][0], bh0, acc0, 0, 0, 0);
      acc1 = __builtin_amdgcn_mfma_f32_16x16x32_bf16(al[1][0], bh0, acc1, 0, 0, 0);
      acc0 = __builtin_amdgcn_mfma_f32_16x16x32_bf16(al[0][1], bh1, acc0, 0, 0, 0);
      acc1 = __builtin_amdgcn_mfma_f32_16x16x32_bf16(al[1][1], bh1, acc1, 0, 0, 0);
#pragma unroll
      for (int rs = 0; rs < 2; ++rs) {
        const f32x4 acc = rs ? acc1 : acc0;
#pragma unroll
        for (int j = 0; j < 4; ++j) {
          float d = fmaf(-2.f, acc[j], sec);
          float nm2 = __builtin_amdgcn_fmed3f(d, m1[rs][j], m2[rs][j]);  // new 2nd-min
          bool lt = d < m1[rs][j];
          m1[rs][j] = lt ? d : m1[rs][j];
          bt[rs][j] = lt ? t : bt[rs][j];
          m2[rs][j] = nm2;
        }
      }
    }
    __syncthreads();
    cur ^= 1;
  }

  // cross-lane reduce over the 16 cols of each row group; lowest-index tie-break
#pragma unroll
  for (int rs = 0; rs < 2; ++rs)
#pragma unroll
    for (int j = 0; j < 4; ++j) {
      float m1j = m1[rs][j], m2j = m2[rs][j];
      int ij = bt[rs][j] * 16 + col;
      for (int msk = 1; msk <= 8; msk <<= 1) {
        float o1 = __shfl_xor(m1j, msk);
        float o2 = __shfl_xor(m2j, msk);
        int oi = __shfl_xor(ij, msk);
        bool take = (o1 < m1j) || (o1 == m1j && oi < ij);
        float hi = take ? m1j : o1;  // losing min1 becomes min2 candidate
        m2j = fminf(fminf(m2j, o2), hi);
        m1j = take ? o1 : m1j;
        ij = take ? oi : ij;
      }
      if (col == 0) {
        const int row = r0 + rs * 16 + g * 4 + j;
        idxo[row] = ij;
        if (m2j - m1j < TAU) {
          int p = atomicAdd((int*)ctl, 1);
          wl[p] = row;
        }
      }
    }
}

// exact fp64 diff-form re-resolution for flagged rows (worklist, ~0.3% of rows)
__global__ __launch_bounds__(256) void k_refine(const float* __restrict__ z,
                                                const float* __restrict__ cb,
                                                const int* __restrict__ wl,
                                                const unsigned int* __restrict__ ctl,
                                                int* __restrict__ idxo) {
  __shared__ float zz[64];
  __shared__ double sd[256];
  __shared__ int si[256];
  const int t = threadIdx.x;
  const int n = (int)ctl[0];
  for (int wi = blockIdx.x; wi < n; wi += 1024) {
    const int row = wl[wi];
    if (t < 16) ((float4*)zz)[t] = ((const float4*)(z + (size_t)row * DIMS))[t];
    __syncthreads();
    const int c0 = t * 4;
    double accd[4] = {0.0, 0.0, 0.0, 0.0};
    for (int ch = 0; ch < 4; ++ch) {
      float zr[16];
#pragma unroll
      for (int q = 0; q < 4; ++q) ((float4*)zr)[q] = ((float4*)zz)[ch * 4 + q];
#pragma unroll
      for (int cc = 0; cc < 4; ++cc) {
        const float* e = cb + (size_t)(c0 + cc) * DIMS + ch * 16;
#pragma unroll
        for (int q = 0; q < 16; ++q) {
          double df = (double)zr[q] - (double)e[q];
          accd[cc] = fma(df, df, accd[cc]);
        }
      }
    }
    double best = 1e300;
    int bi = 0;
#pragma unroll
    for (int cc = 0; cc < 4; ++cc)
      if (accd[cc] < best) { best = accd[cc]; bi = c0 + cc; }
    sd[t] = best;
    si[t] = bi;
    __syncthreads();
    for (int off = 128; off > 0; off >>= 1) {
      if (t < off) {
        double ob = sd[t + off];
        int oi = si[t + off];
        if (ob < sd[t] || (ob == sd[t] && oi < si[t])) { sd[t] = ob; si[t] = oi; }
      }
      __syncthreads();
    }
    if (t == 0) idxo[row] = si[0];
    __syncthreads();
  }
}

// gather + straight-through output (z + (e - z), ref rounding) + loss partials
__global__ __launch_bounds__(256) void k_out(const float* __restrict__ z,
                                             const float* __restrict__ cb,
                                             const int* __restrict__ idxi,
                                             float* __restrict__ out,
                                             float* __restrict__ partials) {
  const int tid = blockIdx.x * 256 + threadIdx.x;  // 262144: quarter-row each
  const int row = tid >> 2;
  const int q = tid & 3;
  const int code = idxi[row];
  const float4* zp = (const float4*)(z + (size_t)row * DIMS + q * 16);
  const float4* ep = (const float4*)(cb + (size_t)code * DIMS + q * 16);
  float4* op = (float4*)(out + (size_t)row * DIMS + q * 16);
  float sse = 0.f;
#pragma unroll
  for (int i = 0; i < 4; ++i) {
    float4 v = zp[i], e = ep[i];
    float dx = e.x - v.x, dy = e.y - v.y, dz = e.z - v.z, dw = e.w - v.w;
    sse = fmaf(dx, dx, sse);
    sse = fmaf(dy, dy, sse);
    sse = fmaf(dz, dz, sse);
    sse = fmaf(dw, dw, sse);
    float4 o;
    o.x = v.x + dx;
    o.y = v.y + dy;
    o.z = v.z + dz;
    o.w = v.w + dw;
    op[i] = o;
  }
  __shared__ float sh[256];
  sh[threadIdx.x] = sse;
  __syncthreads();
  for (int off = 128; off > 0; off >>= 1) {
    if (threadIdx.x < off) sh[threadIdx.x] += sh[threadIdx.x + off];
    __syncthreads();
  }
  if (threadIdx.x == 0) partials[blockIdx.x] = sh[0];
}

__global__ __launch_bounds__(256) void k_loss(const float* __restrict__ partials,
                                              float* __restrict__ out) {
  __shared__ float sh[256];
  const int t = threadIdx.x;
  sh[t] = partials[t] + partials[t + 256] + partials[t + 512] + partials[t + 768];
  __syncthreads();
  for (int off = 128; off > 0; off >>= 1) {
    if (t < off) sh[t] += sh[t + off];
    __syncthreads();
  }
  if (t == 0) {
    // (0.1*mse + mse) * 10 = 11 * SSE / (M*D)
    out[(size_t)M_TOTAL * DIMS] = sh[0] * (11.0f / (float)((size_t)M_TOTAL * DIMS));
  }
}

extern "C" void kernel_launch(void* const* d_in, const int* in_sizes, int n_in,
                              void* d_out, int out_size, void* d_ws, size_t ws_size,
                              hipStream_t stream) {
  const float* z = (const float*)d_in[0];
  const float* cb = (const float*)d_in[1];
  float* out = (float*)d_out;
  float* ws = (float*)d_ws;

  float* se = ws + SE_OFF;
  unsigned int* ctl = (unsigned int*)(ws + CTL_OFF);
  float* partials = ws + PART_OFF;
  unsigned short* pbh = (unsigned short*)(ws + PBH_OFF);
  unsigned short* pbl = (unsigned short*)(ws + PBL_OFF);
  int* wl = (int*)(ws + WL_OFF);
  int* idx = (int*)(ws + IDX_OFF);

  k_prep<<<32, 256, 0, stream>>>(cb, se, ctl, pbh, pbl);
  k_dist<<<M_TOTAL / 128, 256, 0, stream>>>(z, pbh, pbl, se, idx, wl, ctl);
  k_refine<<<1024, 256, 0, stream>>>(z, cb, wl, ctl, idx);
  k_out<<<M_TOTAL / 64, 256, 0, stream>>>(z, cb, idx, out, partials);
  k_loss<<<1, 256, 0, stream>>>(partials, out);
}